// Round 11
// baseline (101.819 us; speedup 1.0000x reference)
//
#include <hip/hip_runtime.h>
#include <math.h>

#define OUTSZ   224
#define NBINS   8
#define NTH     256          // 4 waves: 2 halves x (112 col-pairs + 16 idle)
#define FNTH    256
#define IMG_H   512
#define IMG_W   512
#define HWSZ    (IMG_H * IMG_W)   // 262144
#define SLOTS   256          // per-bin slots (tid-indexed)

// 16-byte vector load at 4-byte alignment (4 consecutive pixels of one row).
typedef float f4u __attribute__((ext_vector_type(4), aligned(4)));

// ---------------------------------------------------------------------------
// r11 = r10 retry (container infra failure, no bench data; cache regs now
// zero-initialized to remove the one latent UB).
// Rolling register row-cache: y-step = roi_h/224 <= 1 for typical boxes, so
// consecutive output rows hit the same (dy=0) or adjacent (dy=1) image row.
// Keep the current row-pair A0/A1/B0/B1 in registers; per iteration a
// WAVE-UNIFORM branch does 0 loads (dy=0), shift+2 loads (dy=1), or 4 loads
// (jump, roi_h>224 generality). Lane remap half=tid>>7 keeps y0 uniform
// among active lanes of every wave (old rq=tid/112 mixed streams in wave 1).
// Retained: r8 256-thr blocks, col-pair dwordx4 + g-vector (r5), interior
// fast path + sign-bit bin decode (r6), conflict-free [bin][tid] LDS +
// 2-barrier shuffle epilogue (r8, conflicts=0), unroll 2 (r9: unroll4 hurt).
// Sums: f32 LDS read-add-write (r1: LDS atomics 3.7x slower).
// Counts: packed register, 8 bits/bin.
// ---------------------------------------------------------------------------
template <int CHUNKS>
__global__ __launch_bounds__(NTH) void velhist_kernel(
    const float* __restrict__ flows,   // (N,2,H,W)
    const float* __restrict__ boxes,   // (M,5)
    float* __restrict__ ws,            // partials (CHUNKS>1): [grid][16]
    float* __restrict__ out)           // (M,8)  (CHUNKS==1 path)
{
    constexpr int RPC = OUTSZ / CHUNKS;   // rows per chunk
    constexpr int RPT = RPC / 2;          // rows per thread (2 row-streams)
    static_assert(RPC % 2 == 0, "2 row-streams need RPC % 2 == 0");
    const int bid   = blockIdx.x;
    const int m     = (CHUNKS == 1) ? bid : (bid / CHUNKS);
    const int chunk = (CHUNKS == 1) ? 0   : (bid - m * CHUNKS);
    const int tid   = threadIdx.x;

    // bins [0,8): sums (main loop). bins [8,16): count scratch (epilogue).
    __shared__ float s_h[2 * NBINS * SLOTS];   // 16 KB
    __shared__ float s_out[2 * NBINS];

    // zero-init sum bins only; count bins are fully overwritten post-loop
#pragma unroll
    for (int b = 0; b < NBINS; ++b)
        s_h[(b << 8) + tid] = 0.0f;

    const float bxf = boxes[m * 5 + 0];
    const float x1  = boxes[m * 5 + 1];
    const float y1  = boxes[m * 5 + 2];
    const float x2  = boxes[m * 5 + 3];
    const float y2  = boxes[m * 5 + 4];
    const int  bidx = (int)bxf;
    const float roi_w = fmaxf(x2 - x1, 1.0f);
    const float roi_h = fmaxf(y2 - y1, 1.0f);

    const float* __restrict__ f0 = flows + (size_t)bidx * 2 * HWSZ;
    const float* __restrict__ f1 = f0 + HWSZ;

    const float GINV = 1.0f / (float)OUTSZ;

    // lane remap: half = tid>>7 (row-stream), cpos = tid&127, active cpos<112.
    // Keeps y0 wave-uniform among active lanes (rolling branch uniformity).
    const int half = tid >> 7;
    const int cpos = tid & 127;
    const bool active = (cpos < 112);
    const int c0 = cpos << 1;

    // ---- per-thread x state (computed once; identity-clamped when interior) ----
    const float px0 = x1 + ((float)c0 + 0.5f) * GINV * roi_w;
    const float px1 = x1 + ((float)c0 + 1.5f) * GINV * roi_w;
    const bool  vx0 = (px0 >= -1.0f) && (px0 <= (float)IMG_W);
    const bool  vx1 = (px1 >= -1.0f) && (px1 <= (float)IMG_W);
    const float pc0 = fminf(fmaxf(px0, 0.0f), (float)(IMG_W - 1));
    const float pc1 = fminf(fmaxf(px1, 0.0f), (float)(IMG_W - 1));
    const int   x00 = min((int)pc0, IMG_W - 2);
    const int   x01 = min((int)pc1, IMG_W - 2);
    const float fx0 = pc0 - (float)x00;
    const float fx1 = pc1 - (float)x01;
    const float wa0 = 1.0f - fx0, wa1 = fx0;      // col0 weights on elems 0,1
    const int   d   = min(x01 - x00, 2);          // element offset of col1
    const float wb0 = 1.0f - fx1, wb1 = fx1;
    const float g0 = (d == 0) ? wb0 : 0.0f;       // col1 4-term weight vector
    const float g1 = (d == 0) ? wb1 : ((d == 1) ? wb0 : 0.0f);
    const float g2 = (d == 1) ? wb1 : ((d == 2) ? wb0 : 0.0f);
    const float g3 = (d == 2) ? wb1 : 0.0f;
    const int   xb = x00;                         // load base (4-px window)

    unsigned long long cnt_pk = 0ULL;   // 8 bits per bin

    __syncthreads();

    const int rowbase = chunk * RPC + half * RPT;

    // Interior-box test (SGPR-uniform): every px,py strictly inside [0,511),
    // all clamps identity, valid always true.
    const bool interior = (x1 >= 0.0f) && (y1 >= 0.0f) &&
                          (x1 + roi_w <= (float)(IMG_W - 1)) &&
                          (y1 + roi_h <= (float)(IMG_H - 1));

    if (active) {
      if (interior) {
        const float kdy = GINV * roi_h;
        const float py0 = fmaf((float)rowbase + 0.5f, kdy, y1);
        float i_f = 0.0f;
        int y0p = -2;                       // force 4-load path on first iter
        f4u A0 = {0,0,0,0}, A1 = {0,0,0,0}; // rolling row-pair cache
        f4u B0 = {0,0,0,0}, B1 = {0,0,0,0};
#pragma unroll 2
        for (int i = 0; i < RPT; ++i) {
            const float py = fmaf(i_f, kdy, py0);
            i_f += 1.0f;
            const int   y0 = (int)py;       // py in [0, 511) strictly
            const float fy = py - (float)y0;

            if (y0 != y0p) {                // wave-uniform among active lanes
                if (y0 == y0p + 1) {        // advance 1: shift + load new row
                    A0 = A1; B0 = B1;
                    const int ir = ((y0 + 1) << 9) + xb;
                    A1 = *reinterpret_cast<const f4u*>(f0 + ir);
                    B1 = *reinterpret_cast<const f4u*>(f1 + ir);
                } else {                    // jump (first iter / roi_h>224)
                    const int i0 = (y0 << 9) + xb;
                    A0 = *reinterpret_cast<const f4u*>(f0 + i0);
                    A1 = *reinterpret_cast<const f4u*>(f0 + i0 + IMG_W);
                    B0 = *reinterpret_cast<const f4u*>(f1 + i0);
                    B1 = *reinterpret_cast<const f4u*>(f1 + i0 + IMG_W);
                }
                y0p = y0;
            }

            const float a0lo = A0.x * wa0 + A0.y * wa1;
            const float a0hi = A1.x * wa0 + A1.y * wa1;
            const float b0lo = B0.x * wa0 + B0.y * wa1;
            const float b0hi = B1.x * wa0 + B1.y * wa1;
            const float a0 = fmaf(fy, a0hi - a0lo, a0lo);   // lerp blend
            const float b0 = fmaf(fy, b0hi - b0lo, b0lo);

            const float a1lo = A0.x * g0 + A0.y * g1 + A0.z * g2 + A0.w * g3;
            const float a1hi = A1.x * g0 + A1.y * g1 + A1.z * g2 + A1.w * g3;
            const float b1lo = B0.x * g0 + B0.y * g1 + B0.z * g2 + B0.w * g3;
            const float b1hi = B1.x * g0 + B1.y * g1 + B1.z * g2 + B1.w * g3;
            const float a1 = fmaf(fy, a1hi - a1lo, a1lo);
            const float b1 = fmaf(fy, b1hi - b1lo, b1lo);

            const float mag0 = __builtin_amdgcn_sqrtf(fmaf(a0, a0, b0 * b0));
            const float mag1 = __builtin_amdgcn_sqrtf(fmaf(a1, a1, b1 * b1));

            // octant decode via sign-bit arithmetic (no valid override here)
            const unsigned au0 = __float_as_uint(a0), bu0 = __float_as_uint(b0);
            const unsigned na0 = au0 >> 31, nb0 = bu0 >> 31;
            const unsigned u0  = na0 ^ nb0;
            const unsigned t0  = ((au0 & 0x7fffffffu) >= (bu0 & 0x7fffffffu)) ? 1u : 0u;
            const int bin0 = (int)(((na0 ^ 1u) << 2) | (u0 << 1) | (u0 ^ t0));

            const unsigned au1 = __float_as_uint(a1), bu1 = __float_as_uint(b1);
            const unsigned na1 = au1 >> 31, nb1 = bu1 >> 31;
            const unsigned u1  = na1 ^ nb1;
            const unsigned t1  = ((au1 & 0x7fffffffu) >= (bu1 & 0x7fffffffu)) ? 1u : 0u;
            const int bin1 = (int)(((na1 ^ 1u) << 2) | (u1 << 1) | (u1 ^ t1));

            s_h[(bin0 << 8) + tid] += mag0;
            s_h[(bin1 << 8) + tid] += mag1;
            cnt_pk += (1ULL << (bin0 << 3)) + (1ULL << (bin1 << 3));
        }
      } else {
        // ---- general path: r8 loop verbatim ----
#pragma unroll 2
        for (int i = 0; i < RPT; ++i) {
            const int row = rowbase + i;
            const float gy  = ((float)row + 0.5f) * GINV;
            const float py  = y1 + gy * roi_h;
            const bool  vy  = (py >= -1.0f) && (py <= (float)IMG_H);
            const float pcy = fminf(fmaxf(py, 0.0f), (float)(IMG_H - 1));
            const int   y0  = min((int)pcy, IMG_H - 2);
            const float fy  = pcy - (float)y0;
            const float wy0 = 1.0f - fy;

            const int i0 = (y0 << 9) + xb;

            const f4u A0 = *reinterpret_cast<const f4u*>(f0 + i0);
            const f4u A1 = *reinterpret_cast<const f4u*>(f0 + i0 + IMG_W);
            const f4u B0 = *reinterpret_cast<const f4u*>(f1 + i0);
            const f4u B1 = *reinterpret_cast<const f4u*>(f1 + i0 + IMG_W);

            const float a0lo = A0.x * wa0 + A0.y * wa1;
            const float a0hi = A1.x * wa0 + A1.y * wa1;
            const float b0lo = B0.x * wa0 + B0.y * wa1;
            const float b0hi = B1.x * wa0 + B1.y * wa1;
            float a0 = wy0 * a0lo + fy * a0hi;
            float b0 = wy0 * b0lo + fy * b0hi;

            const float a1lo = A0.x * g0 + A0.y * g1 + A0.z * g2 + A0.w * g3;
            const float a1hi = A1.x * g0 + A1.y * g1 + A1.z * g2 + A1.w * g3;
            const float b1lo = B0.x * g0 + B0.y * g1 + B0.z * g2 + B0.w * g3;
            const float b1hi = B1.x * g0 + B1.y * g1 + B1.z * g2 + B1.w * g3;
            float a1 = wy0 * a1lo + fy * a1hi;
            float b1 = wy0 * b1lo + fy * b1hi;

            const bool valid0 = vx0 && vy;
            const bool valid1 = vx1 && vy;
            if (!valid0) { a0 = 0.0f; b0 = 0.0f; }
            if (!valid1) { a1 = 0.0f; b1 = 0.0f; }

            const float mag0 = __builtin_amdgcn_sqrtf(a0 * a0 + b0 * b0);
            const float mag1 = __builtin_amdgcn_sqrtf(a1 * a1 + b1 * b1);

            const int p0 = (a0 >= 0.0f) ? 1 : 0;
            const int q0 = (b0 >= 0.0f) ? 1 : 0;
            const int t0 = (fabsf(a0) >= fabsf(b0)) ? 1 : 0;
            const int u0 = p0 ^ q0;
            int bin0 = (p0 << 2) | (u0 << 1) | (u0 ^ t0);
            if (!valid0) bin0 = 4;   // atan2(0,0)=0 -> bin 4

            const int p1 = (a1 >= 0.0f) ? 1 : 0;
            const int q1 = (b1 >= 0.0f) ? 1 : 0;
            const int t1 = (fabsf(a1) >= fabsf(b1)) ? 1 : 0;
            const int u1 = p1 ^ q1;
            int bin1 = (p1 << 2) | (u1 << 1) | (u1 ^ t1);
            if (!valid1) bin1 = 4;

            s_h[(bin0 << 8) + tid] += mag0;
            s_h[(bin1 << 8) + tid] += mag1;
            cnt_pk += (1ULL << (bin0 << 3)) + (1ULL << (bin1 << 3));
        }
      }
    }

    // ---- write packed counts into bins [8,16): every slot covered (all 256
    //      threads write their own tid slot; idle threads write zeros) ----
#pragma unroll
    for (int b = 0; b < NBINS; ++b)
        s_h[((NBINS + b) << 8) + tid] =
            (float)((unsigned)(cnt_pk >> (b << 3)) & 255u);

    __syncthreads();

    // ---- per-wave shuffle reduce: wave wid owns bins [4*wid, 4*wid+4) ----
    {
        const int lane = tid & 63;
        const int wid  = tid >> 6;
#pragma unroll
        for (int k = 0; k < 4; ++k) {
            const int b = (wid << 2) + k;
            float v = s_h[(b << 8) + lane]
                    + s_h[(b << 8) + lane + 64]
                    + s_h[(b << 8) + lane + 128]
                    + s_h[(b << 8) + lane + 192];
#pragma unroll
            for (int off = 32; off >= 1; off >>= 1)
                v += __shfl_down(v, off, 64);
            if (lane == 0) s_out[b] = v;
        }
    }
    __syncthreads();

    if (tid < NBINS) {
        const float s = s_out[tid];
        const float c = s_out[NBINS + tid];
        if (CHUNKS == 1) {
            out[m * NBINS + tid] = (c != 0.0f) ? (s / fmaxf(c, 1.0f)) : 0.0f;
        } else {
            float* p = ws + bid * 16;
            p[tid]     = s;
            p[tid + 8] = c;
        }
    }
}

__global__ __launch_bounds__(FNTH) void finalize_kernel(
    const float* __restrict__ ws, float* __restrict__ out, int M, int chunks)
{
    const int i = blockIdx.x * FNTH + threadIdx.x;
    if (i >= M * NBINS) return;
    const int m = i >> 3;
    const int b = i & 7;
    float s = 0.0f, c = 0.0f;
    for (int ch = 0; ch < chunks; ++ch) {
        const float* p = ws + (size_t)(m * chunks + ch) * 16;
        s += p[b];
        c += p[b + 8];
    }
    out[i] = (c != 0.0f) ? (s / fmaxf(c, 1.0f)) : 0.0f;
}

extern "C" void kernel_launch(void* const* d_in, const int* in_sizes, int n_in,
                              void* d_out, int out_size, void* d_ws, size_t ws_size,
                              hipStream_t stream) {
    const float* flows = (const float*)d_in[0];
    const float* boxes = (const float*)d_in[1];
    float* out = (float*)d_out;
    const int M = in_sizes[1] / 5;               // 512

    const int CH = 4;
    const size_t part_need = (size_t)M * CH * 16 * sizeof(float);      // 128 KB
    if (ws_size >= part_need) {
        velhist_kernel<CH><<<dim3(M * CH), dim3(NTH), 0, stream>>>(
            flows, boxes, (float*)d_ws, nullptr);
        finalize_kernel<<<dim3((M * NBINS + FNTH - 1) / FNTH), dim3(FNTH), 0, stream>>>(
            (const float*)d_ws, out, M, CH);
    } else {
        velhist_kernel<1><<<dim3(M), dim3(NTH), 0, stream>>>(
            flows, boxes, nullptr, out);
    }
}

// Round 13
// 96.885 us; speedup vs baseline: 1.0509x; 1.0509x over previous
//
#include <hip/hip_runtime.h>
#include <math.h>

#define OUTSZ   224
#define NBINS   8
#define NTH     256          // 4 waves: 112 col-pairs x 2 row-streams (+32 idle)
#define ACT     224          // active threads in main loop
#define FNTH    256
#define IMG_H   512
#define IMG_W   512
#define HWSZ    (IMG_H * IMG_W)   // 262144
#define SLOTS   256          // per-bin slots (tid-indexed)

// 16-byte vector load at 4-byte alignment (4 consecutive pixels of one row).
typedef float f4u __attribute__((ext_vector_type(4), aligned(4)));

// ---------------------------------------------------------------------------
// r13 = r12 with the epilogue ownership bug fixed. r12's reduce kept r8's
// 16-bin ownership (b in [0,16)) after the split to 8 logical bins ->
// s_sumA[(b<<8)] OOB reads for b>=8 and s_out[NBINS+b] OOB writes (absmax
// 5951). Fix: each wave owns 2 bins (b = (wid<<1)+k in [0,8)), reduces sum
// (A+B) and count together. The r12 hypothesis itself is untested until now:
// LDS-RMW alias split — sample0 -> s_sumA, sample1 -> s_sumB (distinct
// __shared__ objects, no-alias provable) -> both per-iter LDS reads issue
// together under one wait instead of 2 serialized round-trips.
// Loop body otherwise = r8 verbatim (43.9us proven; r11 rolling cache
// REVERTED: serialized the load stream; r9 unroll-4 REVERTED: +VGPR, no win).
// Sums: f32 LDS read-add-write (r1: ds_add_f32 atomics 3.7x slower).
// Counts: packed register, 8 bits/bin (max 56/thread).
// ---------------------------------------------------------------------------
template <int CHUNKS>
__global__ __launch_bounds__(NTH) void velhist_kernel(
    const float* __restrict__ flows,   // (N,2,H,W)
    const float* __restrict__ boxes,   // (M,5)
    float* __restrict__ ws,            // partials (CHUNKS>1): [grid][16]
    float* __restrict__ out)           // (M,8)  (CHUNKS==1 path)
{
    constexpr int RPC = OUTSZ / CHUNKS;   // rows per chunk
    constexpr int RPT = RPC / 2;          // rows per thread (2 row-streams)
    static_assert(RPC % 2 == 0, "2 row-streams need RPC % 2 == 0");
    const int bid   = blockIdx.x;
    const int m     = (CHUNKS == 1) ? bid : (bid / CHUNKS);
    const int chunk = (CHUNKS == 1) ? 0   : (bid - m * CHUNKS);
    const int tid   = threadIdx.x;

    __shared__ float s_sumA[NBINS * SLOTS];   // 8 KB: sample-0 sums
    __shared__ float s_sumB[NBINS * SLOTS];   // 8 KB: sample-1 sums
    __shared__ float s_cnt [NBINS * SLOTS];   // 8 KB: count unpack (epilogue)
    __shared__ float s_out[2 * NBINS];

    // zero-init sum regions; s_cnt fully overwritten post-loop
#pragma unroll
    for (int b = 0; b < NBINS; ++b) {
        s_sumA[(b << 8) + tid] = 0.0f;
        s_sumB[(b << 8) + tid] = 0.0f;
    }

    const float bxf = boxes[m * 5 + 0];
    const float x1  = boxes[m * 5 + 1];
    const float y1  = boxes[m * 5 + 2];
    const float x2  = boxes[m * 5 + 3];
    const float y2  = boxes[m * 5 + 4];
    const int  bidx = (int)bxf;
    const float roi_w = fmaxf(x2 - x1, 1.0f);
    const float roi_h = fmaxf(y2 - y1, 1.0f);

    const float* __restrict__ f0 = flows + (size_t)bidx * 2 * HWSZ;
    const float* __restrict__ f1 = f0 + HWSZ;

    const float GINV = 1.0f / (float)OUTSZ;

    // thread -> (row-stream rq, col-pair cp);  tid >= 224 idle in main loop
    const int rq = tid / 112;        // 0 or 1 for active threads
    const int cp = tid - rq * 112;
    const int c0 = cp << 1;

    // ---- per-thread x state (computed once; identity-clamped when interior) ----
    const float px0 = x1 + ((float)c0 + 0.5f) * GINV * roi_w;
    const float px1 = x1 + ((float)c0 + 1.5f) * GINV * roi_w;
    const bool  vx0 = (px0 >= -1.0f) && (px0 <= (float)IMG_W);
    const bool  vx1 = (px1 >= -1.0f) && (px1 <= (float)IMG_W);
    const float pc0 = fminf(fmaxf(px0, 0.0f), (float)(IMG_W - 1));
    const float pc1 = fminf(fmaxf(px1, 0.0f), (float)(IMG_W - 1));
    const int   x00 = min((int)pc0, IMG_W - 2);
    const int   x01 = min((int)pc1, IMG_W - 2);
    const float fx0 = pc0 - (float)x00;
    const float fx1 = pc1 - (float)x01;
    const float wa0 = 1.0f - fx0, wa1 = fx0;      // col0 weights on elems 0,1
    const int   d   = min(x01 - x00, 2);          // element offset of col1
    const float wb0 = 1.0f - fx1, wb1 = fx1;
    const float g0 = (d == 0) ? wb0 : 0.0f;       // col1 4-term weight vector
    const float g1 = (d == 0) ? wb1 : ((d == 1) ? wb0 : 0.0f);
    const float g2 = (d == 1) ? wb1 : ((d == 2) ? wb0 : 0.0f);
    const float g3 = (d == 2) ? wb1 : 0.0f;
    const int   xb = x00;                         // load base (4-px window)

    unsigned long long cnt_pk = 0ULL;   // 8 bits per bin

    __syncthreads();

    const int rowbase = chunk * RPC + rq * RPT;

    // Interior-box test (SGPR-uniform): every px,py strictly inside [0,511),
    // all clamps identity, valid always true.
    const bool interior = (x1 >= 0.0f) && (y1 >= 0.0f) &&
                          (x1 + roi_w <= (float)(IMG_W - 1)) &&
                          (y1 + roi_h <= (float)(IMG_H - 1));

    if (tid < ACT) {
      if (interior) {
        const float kdy = GINV * roi_h;
        const float py0 = fmaf((float)rowbase + 0.5f, kdy, y1);
        float i_f = 0.0f;
#pragma unroll 2
        for (int i = 0; i < RPT; ++i) {
            const float py = fmaf(i_f, kdy, py0);
            i_f += 1.0f;
            const int   y0 = (int)py;             // py in [0, 511) strictly
            const float fy = py - (float)y0;
            const int   i0 = (y0 << 9) + xb;

            const f4u A0 = *reinterpret_cast<const f4u*>(f0 + i0);
            const f4u A1 = *reinterpret_cast<const f4u*>(f0 + i0 + IMG_W);
            const f4u B0 = *reinterpret_cast<const f4u*>(f1 + i0);
            const f4u B1 = *reinterpret_cast<const f4u*>(f1 + i0 + IMG_W);

            const float a0lo = A0.x * wa0 + A0.y * wa1;
            const float a0hi = A1.x * wa0 + A1.y * wa1;
            const float b0lo = B0.x * wa0 + B0.y * wa1;
            const float b0hi = B1.x * wa0 + B1.y * wa1;
            const float a0 = fmaf(fy, a0hi - a0lo, a0lo);   // lerp blend
            const float b0 = fmaf(fy, b0hi - b0lo, b0lo);

            const float a1lo = A0.x * g0 + A0.y * g1 + A0.z * g2 + A0.w * g3;
            const float a1hi = A1.x * g0 + A1.y * g1 + A1.z * g2 + A1.w * g3;
            const float b1lo = B0.x * g0 + B0.y * g1 + B0.z * g2 + B0.w * g3;
            const float b1hi = B1.x * g0 + B1.y * g1 + B1.z * g2 + B1.w * g3;
            const float a1 = fmaf(fy, a1hi - a1lo, a1lo);
            const float b1 = fmaf(fy, b1hi - b1lo, b1lo);

            const float mag0 = __builtin_amdgcn_sqrtf(fmaf(a0, a0, b0 * b0));
            const float mag1 = __builtin_amdgcn_sqrtf(fmaf(a1, a1, b1 * b1));

            // octant decode via sign-bit arithmetic (no valid override here)
            const unsigned au0 = __float_as_uint(a0), bu0 = __float_as_uint(b0);
            const unsigned na0 = au0 >> 31, nb0 = bu0 >> 31;
            const unsigned u0  = na0 ^ nb0;
            const unsigned t0  = ((au0 & 0x7fffffffu) >= (bu0 & 0x7fffffffu)) ? 1u : 0u;
            const int bin0 = (int)(((na0 ^ 1u) << 2) | (u0 << 1) | (u0 ^ t0));

            const unsigned au1 = __float_as_uint(a1), bu1 = __float_as_uint(b1);
            const unsigned na1 = au1 >> 31, nb1 = bu1 >> 31;
            const unsigned u1  = na1 ^ nb1;
            const unsigned t1  = ((au1 & 0x7fffffffu) >= (bu1 & 0x7fffffffu)) ? 1u : 0u;
            const int bin1 = (int)(((na1 ^ 1u) << 2) | (u1 << 1) | (u1 ^ t1));

            s_sumA[(bin0 << 8) + tid] += mag0;    // disjoint regions:
            s_sumB[(bin1 << 8) + tid] += mag1;    // reads overlap, one wait
            cnt_pk += (1ULL << (bin0 << 3)) + (1ULL << (bin1 << 3));
        }
      } else {
        // ---- general path: r8 loop verbatim (A/B split applied) ----
#pragma unroll 2
        for (int i = 0; i < RPT; ++i) {
            const int row = rowbase + i;
            const float gy  = ((float)row + 0.5f) * GINV;
            const float py  = y1 + gy * roi_h;
            const bool  vy  = (py >= -1.0f) && (py <= (float)IMG_H);
            const float pcy = fminf(fmaxf(py, 0.0f), (float)(IMG_H - 1));
            const int   y0  = min((int)pcy, IMG_H - 2);
            const float fy  = pcy - (float)y0;
            const float wy0 = 1.0f - fy;

            const int i0 = (y0 << 9) + xb;

            const f4u A0 = *reinterpret_cast<const f4u*>(f0 + i0);
            const f4u A1 = *reinterpret_cast<const f4u*>(f0 + i0 + IMG_W);
            const f4u B0 = *reinterpret_cast<const f4u*>(f1 + i0);
            const f4u B1 = *reinterpret_cast<const f4u*>(f1 + i0 + IMG_W);

            const float a0lo = A0.x * wa0 + A0.y * wa1;
            const float a0hi = A1.x * wa0 + A1.y * wa1;
            const float b0lo = B0.x * wa0 + B0.y * wa1;
            const float b0hi = B1.x * wa0 + B1.y * wa1;
            float a0 = wy0 * a0lo + fy * a0hi;
            float b0 = wy0 * b0lo + fy * b0hi;

            const float a1lo = A0.x * g0 + A0.y * g1 + A0.z * g2 + A0.w * g3;
            const float a1hi = A1.x * g0 + A1.y * g1 + A1.z * g2 + A1.w * g3;
            const float b1lo = B0.x * g0 + B0.y * g1 + B0.z * g2 + B0.w * g3;
            const float b1hi = B1.x * g0 + B1.y * g1 + B1.z * g2 + B1.w * g3;
            float a1 = wy0 * a1lo + fy * a1hi;
            float b1 = wy0 * b1lo + fy * b1hi;

            const bool valid0 = vx0 && vy;
            const bool valid1 = vx1 && vy;
            if (!valid0) { a0 = 0.0f; b0 = 0.0f; }
            if (!valid1) { a1 = 0.0f; b1 = 0.0f; }

            const float mag0 = __builtin_amdgcn_sqrtf(a0 * a0 + b0 * b0);
            const float mag1 = __builtin_amdgcn_sqrtf(a1 * a1 + b1 * b1);

            const int p0 = (a0 >= 0.0f) ? 1 : 0;
            const int q0 = (b0 >= 0.0f) ? 1 : 0;
            const int t0 = (fabsf(a0) >= fabsf(b0)) ? 1 : 0;
            const int u0 = p0 ^ q0;
            int bin0 = (p0 << 2) | (u0 << 1) | (u0 ^ t0);
            if (!valid0) bin0 = 4;   // atan2(0,0)=0 -> bin 4

            const int p1 = (a1 >= 0.0f) ? 1 : 0;
            const int q1 = (b1 >= 0.0f) ? 1 : 0;
            const int t1 = (fabsf(a1) >= fabsf(b1)) ? 1 : 0;
            const int u1 = p1 ^ q1;
            int bin1 = (p1 << 2) | (u1 << 1) | (u1 ^ t1);
            if (!valid1) bin1 = 4;

            s_sumA[(bin0 << 8) + tid] += mag0;
            s_sumB[(bin1 << 8) + tid] += mag1;
            cnt_pk += (1ULL << (bin0 << 3)) + (1ULL << (bin1 << 3));
        }
      }
    }

    // ---- unpack counts into s_cnt: every slot covered (all 256 threads
    //      write their own tid slot; idle threads write zeros) ----
#pragma unroll
    for (int b = 0; b < NBINS; ++b)
        s_cnt[(b << 8) + tid] =
            (float)((unsigned)(cnt_pk >> (b << 3)) & 255u);

    __syncthreads();

    // ---- per-wave shuffle reduce: wave wid owns bins {2*wid, 2*wid+1};
    //      each bin reduces sum (A+B) and count together (b in [0,8)) ----
    {
        const int lane = tid & 63;
        const int wid  = tid >> 6;
#pragma unroll
        for (int k = 0; k < 2; ++k) {
            const int b = (wid << 1) + k;          // 0..7 across 4 waves
            const int base = (b << 8) + lane;
            float v = (s_sumA[base]       + s_sumB[base])
                    + (s_sumA[base + 64]  + s_sumB[base + 64])
                    + (s_sumA[base + 128] + s_sumB[base + 128])
                    + (s_sumA[base + 192] + s_sumB[base + 192]);
            float c = s_cnt[base] + s_cnt[base + 64]
                    + s_cnt[base + 128] + s_cnt[base + 192];
#pragma unroll
            for (int off = 32; off >= 1; off >>= 1) {
                v += __shfl_down(v, off, 64);
                c += __shfl_down(c, off, 64);
            }
            if (lane == 0) { s_out[b] = v; s_out[NBINS + b] = c; }
        }
    }
    __syncthreads();

    if (tid < NBINS) {
        const float s = s_out[tid];
        const float c = s_out[NBINS + tid];
        if (CHUNKS == 1) {
            out[m * NBINS + tid] = (c != 0.0f) ? (s / fmaxf(c, 1.0f)) : 0.0f;
        } else {
            float* p = ws + bid * 16;
            p[tid]     = s;
            p[tid + 8] = c;
        }
    }
}

__global__ __launch_bounds__(FNTH) void finalize_kernel(
    const float* __restrict__ ws, float* __restrict__ out, int M, int chunks)
{
    const int i = blockIdx.x * FNTH + threadIdx.x;
    if (i >= M * NBINS) return;
    const int m = i >> 3;
    const int b = i & 7;
    float s = 0.0f, c = 0.0f;
    for (int ch = 0; ch < chunks; ++ch) {
        const float* p = ws + (size_t)(m * chunks + ch) * 16;
        s += p[b];
        c += p[b + 8];
    }
    out[i] = (c != 0.0f) ? (s / fmaxf(c, 1.0f)) : 0.0f;
}

extern "C" void kernel_launch(void* const* d_in, const int* in_sizes, int n_in,
                              void* d_out, int out_size, void* d_ws, size_t ws_size,
                              hipStream_t stream) {
    const float* flows = (const float*)d_in[0];
    const float* boxes = (const float*)d_in[1];
    float* out = (float*)d_out;
    const int M = in_sizes[1] / 5;               // 512

    const int CH = 4;
    const size_t part_need = (size_t)M * CH * 16 * sizeof(float);      // 128 KB
    if (ws_size >= part_need) {
        velhist_kernel<CH><<<dim3(M * CH), dim3(NTH), 0, stream>>>(
            flows, boxes, (float*)d_ws, nullptr);
        finalize_kernel<<<dim3((M * NBINS + FNTH - 1) / FNTH), dim3(FNTH), 0, stream>>>(
            (const float*)d_ws, out, M, CH);
    } else {
        velhist_kernel<1><<<dim3(M), dim3(NTH), 0, stream>>>(
            flows, boxes, nullptr, out);
    }
}